// Round 5
// baseline (389.178 us; speedup 1.0000x reference)
//
#include <hip/hip_runtime.h>
#include <math.h>

#define N_NODES 20000
#define N_EDGES 160000
#define NODE_DIM 64
#define EDGE_DIM 16
#define H 32
#define STEPS 3
#define UROW 544   // U[v][c]: c = i*16+d for c<512 (i=c>>4,d=c&15); c=512+i is bias plane

// ---------------------------------------------------------------------------
// CSR-by-src build (once per call): hist -> 2-level scan -> atomic fill
// emitting src-sorted eperm/dst2; ef permuted into ef2 in sorted order.
// ---------------------------------------------------------------------------
__global__ void hist_kernel(const int* __restrict__ ei, int* __restrict__ deg) {
    int e = blockIdx.x * 256 + threadIdx.x;
    if (e < N_EDGES) atomicAdd(&deg[ei[e]], 1);   // row 0 = src
}

__global__ void scan_a_kernel(const int* __restrict__ deg,
                              int* __restrict__ part, int* __restrict__ bsum) {
    __shared__ int s[256];
    int v = blockIdx.x * 256 + threadIdx.x;
    int x = (v < N_NODES) ? deg[v] : 0;
    s[threadIdx.x] = x;
    __syncthreads();
    for (int off = 1; off < 256; off <<= 1) {
        int t = (threadIdx.x >= off) ? s[threadIdx.x - off] : 0;
        __syncthreads();
        s[threadIdx.x] += t;
        __syncthreads();
    }
    if (v < N_NODES) part[v] = s[threadIdx.x] - x;
    if (threadIdx.x == 255) bsum[blockIdx.x] = s[255];
}

__global__ void scan_b_kernel(int* __restrict__ rowptr,
                              const int* __restrict__ bsum,
                              int* __restrict__ cursor) {
    __shared__ int boff[80];
    if (threadIdx.x == 0) {
        int run = 0;
        for (int b = 0; b < 79; ++b) { boff[b] = run; run += bsum[b]; }
    }
    __syncthreads();
    for (int v = threadIdx.x; v < N_NODES; v += 256) {
        int r = rowptr[v] + boff[v >> 8];
        rowptr[v] = r;
        cursor[v] = r;
    }
    if (threadIdx.x == 0) rowptr[N_NODES] = N_EDGES;
}

__global__ void fill_kernel(const int* __restrict__ ei, int* __restrict__ cursor,
                            int* __restrict__ eperm, int* __restrict__ dst2) {
    int e = blockIdx.x * 256 + threadIdx.x;
    if (e < N_EDGES) {
        int s = ei[e];
        int slot = atomicAdd(&cursor[s], 1);
        eperm[slot] = e;
        dst2[slot]  = ei[N_EDGES + e];
    }
}

__global__ void permute_ef_kernel(const float* __restrict__ ef,
                                  const int* __restrict__ eperm,
                                  float* __restrict__ ef2) {
    int t = blockIdx.x * 256 + threadIdx.x;
    if (t < N_EDGES * EDGE_DIM) {
        int j = t >> 4;
        int d = t & 15;
        ef2[t] = ef[eperm[j] * EDGE_DIM + d];
    }
}

// ---------------------------------------------------------------------------
// node projection: h = node_feat @ W_np.T + b_np
// ---------------------------------------------------------------------------
__global__ void node_proj_kernel(const float* __restrict__ nf,
                                 const float* __restrict__ W,
                                 const float* __restrict__ b,
                                 float* __restrict__ h) {
    int tid = blockIdx.x * blockDim.x + threadIdx.x;
    if (tid >= N_NODES * H) return;
    int v = tid >> 5;
    int i = tid & 31;
    const float* __restrict__ row = nf + v * NODE_DIM;
    const float* __restrict__ w   = W + i * NODE_DIM;
    float acc = b[i];
#pragma unroll
    for (int d = 0; d < NODE_DIM; ++d) acc = fmaf(row[d], w[d], acc);
    h[tid] = acc;
}

// ---------------------------------------------------------------------------
// U precompute v3 (unchanged from R4 — measured adequate):
//   U[v, c] = sum_k Wx[k][c] * h[v,k], W in registers, h via LDS broadcast.
// ---------------------------------------------------------------------------
__global__ __launch_bounds__(576)
void u_precompute_kernel(const float* __restrict__ We,
                         const float* __restrict__ be,
                         const float* __restrict__ h,
                         float* __restrict__ U) {
    __shared__ float hs[32 * 32];   // 4 KB
    int t = threadIdx.x;
    int c = t;

    float wreg[32];
    if (c < 512) {
        int i = c >> 4, d = c & 15;
#pragma unroll
        for (int k = 0; k < H; ++k) wreg[k] = We[(i * H + k) * EDGE_DIM + d];
    } else if (c < UROW) {
        int i = c - 512;
#pragma unroll
        for (int k = 0; k < H; ++k) wreg[k] = be[i * H + k];
    }

    for (int v0 = blockIdx.x * 32; v0 < N_NODES; v0 += gridDim.x * 32) {
        __syncthreads();
        for (int idx = t; idx < 32 * 32; idx += 576) hs[idx] = h[v0 * H + idx];
        __syncthreads();

        for (int n = 0; n < 32; n += 2) {
            const float4* __restrict__ hp0 = (const float4*)(hs + n * H);
            const float4* __restrict__ hp1 = (const float4*)(hs + (n + 1) * H);
            float a0 = 0.f, a1 = 0.f;
#pragma unroll
            for (int kk = 0; kk < 8; ++kk) {
                float4 q0 = hp0[kk];
                float4 q1 = hp1[kk];
                a0 = fmaf(wreg[4 * kk + 0], q0.x, a0);
                a1 = fmaf(wreg[4 * kk + 0], q1.x, a1);
                a0 = fmaf(wreg[4 * kk + 1], q0.y, a0);
                a1 = fmaf(wreg[4 * kk + 1], q1.y, a1);
                a0 = fmaf(wreg[4 * kk + 2], q0.z, a0);
                a1 = fmaf(wreg[4 * kk + 2], q1.z, a1);
                a0 = fmaf(wreg[4 * kk + 3], q0.w, a0);
                a1 = fmaf(wreg[4 * kk + 3], q1.w, a1);
            }
            if (c < UROW) {
                U[(size_t)(v0 + n)     * UROW + c] = a0;
                U[(size_t)(v0 + n + 1) * UROW + c] = a1;
            }
        }
    }
}

// ---------------------------------------------------------------------------
// Edge message v2: one 32-lane group per SRC node. U row loaded ONCE into
// registers (lane i holds U[s,i,0..15] + bias = 17 VGPRs), then the src's
// out-edges (contiguous in sorted order) are streamed: coalesced ef2/dst2
// reads, 16 shfl + 17 fma, one atomic per edge. U traffic = exactly 43.5 MB,
// fully coalesced; no dependence on cross-block cache reuse.
// 2500 blocks x 8 groups = 20000 groups = one per src.
// ---------------------------------------------------------------------------
__global__ __launch_bounds__(256)
void edge_msg_kernel(const int* __restrict__ rowptr,
                     const int* __restrict__ dst2,
                     const float* __restrict__ ef2,
                     const float* __restrict__ U,
                     float* __restrict__ m) {
    int lane = threadIdx.x & 31;
    int s    = (blockIdx.x * blockDim.x + threadIdx.x) >> 5;   // src node
    if (s >= N_NODES) return;

    int e0 = rowptr[s];
    int e1 = rowptr[s + 1];
    if (e0 == e1) return;

    const float* __restrict__ Up = U + (size_t)s * UROW;
    const float4* __restrict__ Ur = (const float4*)(Up + lane * EDGE_DIM);
    float4 u0 = Ur[0];
    float4 u1 = Ur[1];
    float4 u2 = Ur[2];
    float4 u3 = Ur[3];
    float bias = Up[512 + lane];

    for (int j = e0; j < e1; ++j) {
        float efv = (lane < EDGE_DIM) ? ef2[j * EDGE_DIM + lane] : 0.f;
        int dd = dst2[j];
        float msg = bias;
        msg = fmaf(__shfl(efv,  0, 32), u0.x, msg);
        msg = fmaf(__shfl(efv,  1, 32), u0.y, msg);
        msg = fmaf(__shfl(efv,  2, 32), u0.z, msg);
        msg = fmaf(__shfl(efv,  3, 32), u0.w, msg);
        msg = fmaf(__shfl(efv,  4, 32), u1.x, msg);
        msg = fmaf(__shfl(efv,  5, 32), u1.y, msg);
        msg = fmaf(__shfl(efv,  6, 32), u1.z, msg);
        msg = fmaf(__shfl(efv,  7, 32), u1.w, msg);
        msg = fmaf(__shfl(efv,  8, 32), u2.x, msg);
        msg = fmaf(__shfl(efv,  9, 32), u2.y, msg);
        msg = fmaf(__shfl(efv, 10, 32), u2.z, msg);
        msg = fmaf(__shfl(efv, 11, 32), u2.w, msg);
        msg = fmaf(__shfl(efv, 12, 32), u3.x, msg);
        msg = fmaf(__shfl(efv, 13, 32), u3.y, msg);
        msg = fmaf(__shfl(efv, 14, 32), u3.z, msg);
        msg = fmaf(__shfl(efv, 15, 32), u3.w, msg);
        atomicAdd(&m[dd * H + lane], msg);
    }
}

// ---------------------------------------------------------------------------
// GRU cell + self-zero of m for the next step (unchanged from R4).
// ---------------------------------------------------------------------------
__global__ __launch_bounds__(256)
void gru_kernel(const float* __restrict__ Wih,
                const float* __restrict__ Whh,
                const float* __restrict__ bih,
                const float* __restrict__ bhh,
                float* __restrict__ m,
                const float* __restrict__ h,
                float* __restrict__ hout) {
    __shared__ float WihT[H * 3 * H];
    __shared__ float WhhT[H * 3 * H];
    for (int idx = threadIdx.x; idx < 3 * H * H; idx += 256) {
        int row = idx >> 5;
        int k   = idx & 31;
        WihT[k * (3 * H) + row] = Wih[idx];
        WhhT[k * (3 * H) + row] = Whh[idx];
    }
    __syncthreads();

    int lane = threadIdx.x & 31;
    int grp  = threadIdx.x >> 5;

    for (int v0 = blockIdx.x * 8; v0 < N_NODES; v0 += gridDim.x * 8) {
        int v = v0 + grp;
        if (v < N_NODES) {
            float mv = m[v * H + lane];
            m[v * H + lane] = 0.f;          // pre-zero for next step's atomics
            float hv = h[v * H + lane];
            float ir = bih[lane], iz = bih[H + lane], in_ = bih[2 * H + lane];
            float hr = bhh[lane], hz = bhh[H + lane], hn  = bhh[2 * H + lane];
#pragma unroll
            for (int k = 0; k < H; ++k) {
                float mk = __shfl(mv, k, 32);
                float hk = __shfl(hv, k, 32);
                ir  = fmaf(WihT[k * 96 + lane],          mk, ir);
                iz  = fmaf(WihT[k * 96 + H + lane],      mk, iz);
                in_ = fmaf(WihT[k * 96 + 2 * H + lane],  mk, in_);
                hr  = fmaf(WhhT[k * 96 + lane],          hk, hr);
                hz  = fmaf(WhhT[k * 96 + H + lane],      hk, hz);
                hn  = fmaf(WhhT[k * 96 + 2 * H + lane],  hk, hn);
            }
            float r  = 1.f / (1.f + __expf(-(ir + hr)));
            float z  = 1.f / (1.f + __expf(-(iz + hz)));
            float nn = tanhf(in_ + r * hn);
            hout[v * H + lane] = (1.f - z) * nn + z * hv;
        }
    }
}

// ---------------------------------------------------------------------------
extern "C" void kernel_launch(void* const* d_in, const int* in_sizes, int n_in,
                              void* d_out, int out_size, void* d_ws, size_t ws_size,
                              hipStream_t stream) {
    const float* node_feat = (const float*)d_in[0];
    const int*   edge_idx  = (const int*)  d_in[1];
    const float* edge_feat = (const float*)d_in[2];
    const float* W_np      = (const float*)d_in[3];
    const float* b_np      = (const float*)d_in[4];
    const float* W_e       = (const float*)d_in[5];
    const float* b_e       = (const float*)d_in[6];
    const float* W_ih      = (const float*)d_in[7];
    const float* W_hh      = (const float*)d_in[8];
    const float* b_ih      = (const float*)d_in[9];
    const float* b_hh      = (const float*)d_in[10];

    float* h      = (float*)d_ws;                         // 640000
    float* m      = h + (size_t)N_NODES * H;              // 640000
    float* U      = m + (size_t)N_NODES * H;              // 10,880,000
    float* ef2    = U + (size_t)N_NODES * UROW;           // 2,560,000
    int*   rowptr = (int*)(ef2 + (size_t)N_EDGES * EDGE_DIM); // N+1
    int*   cursor = rowptr + (N_NODES + 1);               // N
    int*   bsum   = cursor + N_NODES;                     // 80
    int*   eperm  = bsum + 80;                            // E
    int*   dst2   = eperm + N_EDGES;                      // E
    float* out    = (float*)d_out;

    // ---- one-time: zero m, build src-sorted edge arrays ----
    hipMemsetAsync(m, 0, (size_t)N_NODES * H * sizeof(float), stream);
    hipMemsetAsync(cursor, 0, N_NODES * sizeof(int), stream);
    hist_kernel<<<(N_EDGES + 255) / 256, 256, 0, stream>>>(edge_idx, cursor);
    scan_a_kernel<<<(N_NODES + 255) / 256, 256, 0, stream>>>(cursor, rowptr, bsum);
    scan_b_kernel<<<1, 256, 0, stream>>>(rowptr, bsum, cursor);
    fill_kernel<<<(N_EDGES + 255) / 256, 256, 0, stream>>>(edge_idx, cursor,
                                                           eperm, dst2);
    permute_ef_kernel<<<(N_EDGES * EDGE_DIM + 255) / 256, 256, 0, stream>>>(
        edge_feat, eperm, ef2);

    // ---- h0 ----
    node_proj_kernel<<<(N_NODES * H + 255) / 256, 256, 0, stream>>>(
        node_feat, W_np, b_np, h);

    // ---- 3 propagation steps ----
    for (int step = 0; step < STEPS; ++step) {
        u_precompute_kernel<<<313, 576, 0, stream>>>(W_e, b_e, h, U);
        edge_msg_kernel<<<(N_NODES * H + 255) / 256, 256, 0, stream>>>(
            rowptr, dst2, ef2, U, m);
        float* dst_h = (step == STEPS - 1) ? out : h;
        gru_kernel<<<256, 256, 0, stream>>>(W_ih, W_hh, b_ih, b_hh, m, h, dst_h);
    }
}